// Round 5
// baseline (54.460 us; speedup 1.0000x reference)
//
#include <hip/hip_runtime.h>
#include <hip/hip_bf16.h>

typedef __attribute__((ext_vector_type(8))) short short8v;
typedef __attribute__((ext_vector_type(4))) float f32x4;

// Fused: out = feat + bias (blocks [0,initB)), Wz bf16 pack (blocks [initB, ...))
// Wz column mapping (K-permutation): k = t*32 + g*8 + j  <->  c = (g>>1)*8 + t,
// i = (g&1)*8 + j  (t<8);  t==8: k=256+g*8+j -> be row g*8+j (g<2), 0 pad.
__global__ __launch_bounds__(256) void setup_kernel(
    const float* __restrict__ feat, const float* __restrict__ bias,
    const float* __restrict__ We, const float* __restrict__ be,
    float* __restrict__ out, unsigned short* __restrict__ wp,
    int n_elems, int initB) {
  if ((int)blockIdx.x < initB) {
    int g = blockIdx.x * 256 + threadIdx.x;
    int base = g * 4;
    if (base < n_elems) {
      float4 f = *reinterpret_cast<const float4*>(feat + base);
      const float4* b4 = reinterpret_cast<const float4*>(bias);
      float4 b = b4[g & 3];
      float4 o;
      o.x = f.x + b.x; o.y = f.y + b.y; o.z = f.z + b.z; o.w = f.w + b.w;
      *reinterpret_cast<float4*>(out + base) = o;
    }
  } else {
    int idx = (blockIdx.x - initB) * 256 + threadIdx.x;
    if (idx < 9 * 4 * 16 * 8) {
      int j = idx & 7, n = (idx >> 3) & 15, gg = (idx >> 7) & 3, t = idx >> 9;
      float v = 0.f;
      if (t < 8) {
        int c = (gg >> 1) * 8 + t;
        int i = (gg & 1) * 8 + j;
        v = We[c * 256 + i * 16 + n];
      } else if (gg < 2) {
        v = be[(gg * 8 + j) * 16 + n];
      }
      __hip_bfloat16 b = __float2bfloat16(v);
      wp[idx] = __builtin_bit_cast(unsigned short, b);
    }
  }
}

// One 16-edge tile per wave. Lane (g=lane>>4, m=lane&15):
//   A-frag: edge m, K-slice k = g*8+j; Z[k] = ef[(g>>1)*8 + t] * h[(g&1)*8 + j]
//   B-frag Bf[t] packed so lane reads wp[t*64 + lane]*8 (contiguous 1KB/t).
//   D: col = m, row = g*4+r.
__global__ __launch_bounds__(256) void edge_mfma_kernel(
    const float* __restrict__ feat, const float* __restrict__ efeat,
    const int* __restrict__ src, const int* __restrict__ dst,
    const unsigned short* __restrict__ wp,
    float* __restrict__ out, int E) {
  int wave = blockIdx.x * 4 + (threadIdx.x >> 6);
  int lane = threadIdx.x & 63;
  int g = lane >> 4;
  int m = lane & 15;
  int p = g >> 1;        // ef slice: ef[p*8 .. p*8+7]
  int hb = (g & 1) * 8;  // h slice:  h[hb .. hb+7]

  int e0 = wave * 16;
  if (e0 >= E) return;

  short8v Bf[9];
#pragma unroll
  for (int t = 0; t < 9; ++t)
    Bf[t] = *reinterpret_cast<const short8v*>(wp + ((size_t)(t * 64 + lane)) * 8);

  float4 E0v, E1v, H0v, H1v;
  int4 dd;

  if (e0 + 16 <= E) {
    int e = e0 + m;
    int s = src[e];
    const float4* efp = reinterpret_cast<const float4*>(efeat + (size_t)e * 16 + p * 8);
    E0v = efp[0]; E1v = efp[1];
    dd = *reinterpret_cast<const int4*>(dst + e0 + g * 4);
    const float4* hp = reinterpret_cast<const float4*>(feat + (size_t)s * 16 + hb);
    H0v = hp[0]; H1v = hp[1];
  } else {
    int e = e0 + m;
    float vmask = (e < E) ? 1.f : 0.f;
    int ec = (e < E) ? e : (E - 1);
    int s = src[ec];
    const float4* efp = reinterpret_cast<const float4*>(efeat + (size_t)ec * 16 + p * 8);
    E0v = efp[0]; E1v = efp[1];
    E0v.x *= vmask; E0v.y *= vmask; E0v.z *= vmask; E0v.w *= vmask;
    E1v.x *= vmask; E1v.y *= vmask; E1v.z *= vmask; E1v.w *= vmask;
    const float4* hp = reinterpret_cast<const float4*>(feat + (size_t)s * 16 + hb);
    H0v = hp[0]; H1v = hp[1];
    int b = e0 + g * 4;
    dd.x = dst[min(b + 0, E - 1)];
    dd.y = dst[min(b + 1, E - 1)];
    dd.z = dst[min(b + 2, E - 1)];
    dd.w = dst[min(b + 3, E - 1)];
  }

  float efs[8] = {E0v.x, E0v.y, E0v.z, E0v.w, E1v.x, E1v.y, E1v.z, E1v.w};
  float h[8]   = {H0v.x, H0v.y, H0v.z, H0v.w, H1v.x, H1v.y, H1v.z, H1v.w};

  f32x4 acc = {0.f, 0.f, 0.f, 0.f};
#pragma unroll
  for (int t = 0; t < 8; ++t) {
    short8v A;
#pragma unroll
    for (int jj = 0; jj < 8; ++jj) {
      float prod = efs[t] * h[jj];                 // fp32 product, single rounding
      __hip_bfloat16 bb = __float2bfloat16(prod);
      A[jj] = __builtin_bit_cast(short, bb);
    }
    acc = __builtin_amdgcn_mfma_f32_16x16x32_bf16(A, Bf[t], acc, 0, 0, 0);
  }
  {  // be passthrough K-tile (Z = h[i] at k=256+i), zero pad k>=272
    short8v A;
#pragma unroll
    for (int jj = 0; jj < 8; ++jj) {
      float hv = (g < 2) ? h[jj] : 0.f;
      __hip_bfloat16 bb = __float2bfloat16(hv);
      A[jj] = __builtin_bit_cast(short, bb);
    }
    acc = __builtin_amdgcn_mfma_f32_16x16x32_bf16(A, Bf[8], acc, 0, 0, 0);
  }

  // dst sorted -> run-combine then one atomic per run (per group g, rows g*4+r)
  float run = acc[0];
  int cur = dd.x;
  if (dd.y == cur) run += acc[1];
  else { unsafeAtomicAdd(out + (size_t)cur * 16 + m, run); cur = dd.y; run = acc[1]; }
  if (dd.z == cur) run += acc[2];
  else { unsafeAtomicAdd(out + (size_t)cur * 16 + m, run); cur = dd.z; run = acc[2]; }
  if (dd.w == cur) run += acc[3];
  else { unsafeAtomicAdd(out + (size_t)cur * 16 + m, run); cur = dd.w; run = acc[3]; }
  unsafeAtomicAdd(out + (size_t)cur * 16 + m, run);
}

extern "C" void kernel_launch(void* const* d_in, const int* in_sizes, int n_in,
                              void* d_out, int out_size, void* d_ws, size_t ws_size,
                              hipStream_t stream) {
  const float* feat  = (const float*)d_in[0];
  const float* efeat = (const float*)d_in[1];
  const float* We    = (const float*)d_in[2];
  const float* be    = (const float*)d_in[3];
  const float* bias  = (const float*)d_in[4];
  const int*   src   = (const int*)d_in[5];
  const int*   dst   = (const int*)d_in[6];
  float* out = (float*)d_out;

  int E = in_sizes[5];
  int n_elems = out_size;  // 50000*16

  int groups = (n_elems + 3) / 4;
  int initB = (groups + 255) / 256;
  int prepB = (9 * 4 * 16 * 8 + 255) / 256;
  setup_kernel<<<initB + prepB, 256, 0, stream>>>(feat, bias, We, be, out,
                                                  (unsigned short*)d_ws, n_elems, initB);

  int tiles = (E + 15) / 16;       // one wave per tile
  int blocks = (tiles + 3) / 4;    // 4 waves per 256-thread block
  edge_mfma_kernel<<<blocks, 256, 0, stream>>>(feat, efeat, src, dst,
                                               (const unsigned short*)d_ws, out, E);
}

// Round 6
// 51.427 us; speedup vs baseline: 1.0590x; 1.0590x over previous
//
#include <hip/hip_runtime.h>
#include <hip/hip_bf16.h>

typedef __attribute__((ext_vector_type(8))) short short8v;
typedef __attribute__((ext_vector_type(4))) float f32x4;

#define NBLK 1024
#define WT (NBLK * 4)  // total waves (4 waves / 256-thread block)

// Fused: out = feat + bias (blocks [0,initB)), Wz bf16 pack (blocks [initB, ...))
// Wz column mapping (K-permutation): k = t*32 + g*8 + j  <->  c = (g>>1)*8 + t,
// i = (g&1)*8 + j  (t<8);  t==8: k=256+g*8+j -> be row g*8+j (g<2), 0 pad.
__global__ __launch_bounds__(256) void setup_kernel(
    const float* __restrict__ feat, const float* __restrict__ bias,
    const float* __restrict__ We, const float* __restrict__ be,
    float* __restrict__ out, unsigned short* __restrict__ wp,
    int n_elems, int initB) {
  if ((int)blockIdx.x < initB) {
    int g = blockIdx.x * 256 + threadIdx.x;
    int base = g * 4;
    if (base < n_elems) {
      float4 f = *reinterpret_cast<const float4*>(feat + base);
      const float4* b4 = reinterpret_cast<const float4*>(bias);
      float4 b = b4[g & 3];
      float4 o;
      o.x = f.x + b.x; o.y = f.y + b.y; o.z = f.z + b.z; o.w = f.w + b.w;
      *reinterpret_cast<float4*>(out + base) = o;
    }
  } else {
    int idx = (blockIdx.x - initB) * 256 + threadIdx.x;
    if (idx < 9 * 4 * 16 * 8) {
      int j = idx & 7, n = (idx >> 3) & 15, gg = (idx >> 7) & 3, t = idx >> 9;
      float v = 0.f;
      if (t < 8) {
        int c = (gg >> 1) * 8 + t;
        int i = (gg & 1) * 8 + j;
        v = We[c * 256 + i * 16 + n];
      } else if (gg < 2) {
        v = be[(gg * 8 + j) * 16 + n];
      }
      __hip_bfloat16 b = __float2bfloat16(v);
      wp[idx] = __builtin_bit_cast(unsigned short, b);
    }
  }
}

// A-frag: edge m=lane&15, K-slice k=g*8+j; Z[k] = ef[(g>>1)*8+t] * h[(g&1)*8+j]
// B-frag Bf[t]: lane reads wp[(t*64+lane)*8] (contiguous). D: col=m, row=g*4+r.
__device__ __forceinline__ void compute_tile(
    float4 E0, float4 E1, float4 H0, float4 H1, int4 dd,
    int g, int m, const short8v* Bf, float* __restrict__ out) {
  float efs[8] = {E0.x, E0.y, E0.z, E0.w, E1.x, E1.y, E1.z, E1.w};
  float h[8]   = {H0.x, H0.y, H0.z, H0.w, H1.x, H1.y, H1.z, H1.w};
  f32x4 acc = {0.f, 0.f, 0.f, 0.f};
#pragma unroll
  for (int t = 0; t < 8; ++t) {
    short8v A;
#pragma unroll
    for (int jj = 0; jj < 8; ++jj) {
      float prod = efs[t] * h[jj];                // fp32 product, single rounding
      __hip_bfloat16 bb = __float2bfloat16(prod);
      A[jj] = __builtin_bit_cast(short, bb);
    }
    acc = __builtin_amdgcn_mfma_f32_16x16x32_bf16(A, Bf[t], acc, 0, 0, 0);
  }
  {  // be passthrough K-tile (Z = h[i] at k=256+i), zero pad k>=272
    short8v A;
#pragma unroll
    for (int jj = 0; jj < 8; ++jj) {
      float hv = (g < 2) ? h[jj] : 0.f;
      __hip_bfloat16 bb = __float2bfloat16(hv);
      A[jj] = __builtin_bit_cast(short, bb);
    }
    acc = __builtin_amdgcn_mfma_f32_16x16x32_bf16(A, Bf[8], acc, 0, 0, 0);
  }
  // dst sorted -> run-combine then one atomic per run
  float run = acc[0];
  int cur = dd.x;
  if (dd.y == cur) run += acc[1];
  else { unsafeAtomicAdd(out + (size_t)cur * 16 + m, run); cur = dd.y; run = acc[1]; }
  if (dd.z == cur) run += acc[2];
  else { unsafeAtomicAdd(out + (size_t)cur * 16 + m, run); cur = dd.z; run = acc[2]; }
  if (dd.w == cur) run += acc[3];
  else { unsafeAtomicAdd(out + (size_t)cur * 16 + m, run); cur = dd.w; run = acc[3]; }
  unsafeAtomicAdd(out + (size_t)cur * 16 + m, run);
}

__global__ __launch_bounds__(256) void edge_mfma_kernel(
    const float* __restrict__ feat, const float* __restrict__ efeat,
    const int* __restrict__ src, const int* __restrict__ dst,
    const unsigned short* __restrict__ wp,
    float* __restrict__ out, int E) {
  int wave = blockIdx.x * 4 + (threadIdx.x >> 6);
  int lane = threadIdx.x & 63;
  int g = lane >> 4;
  int m = lane & 15;
  int p = g >> 1;        // ef slice
  int hh = g & 1;        // h slice selector

  int ntiles = (E + 15) >> 4;
  if (wave >= ntiles) return;
  const bool partialF = (E & 15) != 0;
  const int lastT = ntiles - 1;

  short8v Bf[9];
#pragma unroll
  for (int t = 0; t < 9; ++t)
    Bf[t] = *reinterpret_cast<const short8v*>(wp + (unsigned)(t * 64 + lane) * 8);

  const float4* ef4 = reinterpret_cast<const float4*>(efeat);
  const float4* f4  = reinterpret_cast<const float4*>(feat);
  const int4*   d4  = reinterpret_cast<const int4*>(dst);

  // ---- prologue: load current tile fully ----
  int tile = wave;
  float4 E0, E1, H0, H1;
  int4 dd;
  if (__builtin_expect(partialF && tile == lastT, 0)) {
    int e = tile * 16 + m;
    int ec = min(e, E - 1);
    E0 = ef4[(unsigned)ec * 4 + p * 2]; E1 = ef4[(unsigned)ec * 4 + p * 2 + 1];
    if (e >= E) { E0 = make_float4(0.f,0.f,0.f,0.f); E1 = make_float4(0.f,0.f,0.f,0.f); }
    int s = src[ec];
    H0 = f4[(unsigned)s * 4 + hh * 2]; H1 = f4[(unsigned)s * 4 + hh * 2 + 1];
    int b = tile * 16 + g * 4;
    dd.x = dst[min(b + 0, E - 1)]; dd.y = dst[min(b + 1, E - 1)];
    dd.z = dst[min(b + 2, E - 1)]; dd.w = dst[min(b + 3, E - 1)];
  } else {
    int e = tile * 16 + m;
    int s = src[e];
    E0 = ef4[(unsigned)e * 4 + p * 2]; E1 = ef4[(unsigned)e * 4 + p * 2 + 1];
    dd = d4[(unsigned)tile * 4 + g];
    H0 = f4[(unsigned)s * 4 + hh * 2]; H1 = f4[(unsigned)s * 4 + hh * 2 + 1];
  }

  int tile1 = tile + WT;
  int s1 = 0;
  if (tile1 < ntiles) s1 = src[min(tile1 * 16 + m, E - 1)];

  // ---- steady state: unconditional prefetch (payload n+1, src n+2), then compute n ----
  while (tile1 < ntiles) {
    int tile2 = tile1 + WT;

    float4 E0n, E1n, H0n, H1n;
    int4 ddn;
    if (__builtin_expect(partialF && tile1 == lastT, 0)) {
      int e = tile1 * 16 + m;
      int ec = min(e, E - 1);
      E0n = ef4[(unsigned)ec * 4 + p * 2]; E1n = ef4[(unsigned)ec * 4 + p * 2 + 1];
      if (e >= E) { E0n = make_float4(0.f,0.f,0.f,0.f); E1n = make_float4(0.f,0.f,0.f,0.f); }
      int b = tile1 * 16 + g * 4;
      ddn.x = dst[min(b + 0, E - 1)]; ddn.y = dst[min(b + 1, E - 1)];
      ddn.z = dst[min(b + 2, E - 1)]; ddn.w = dst[min(b + 3, E - 1)];
    } else {
      int e = tile1 * 16 + m;
      E0n = ef4[(unsigned)e * 4 + p * 2]; E1n = ef4[(unsigned)e * 4 + p * 2 + 1];
      ddn = d4[(unsigned)tile1 * 4 + g];
    }
    // gather for tile1 — s1 was loaded a full iteration ago, its wait is free
    H0n = f4[(unsigned)s1 * 4 + hh * 2]; H1n = f4[(unsigned)s1 * 4 + hh * 2 + 1];
    // src for tile2 (clamped; unused if loop exits)
    int s2 = src[min(tile2 * 16 + m, E - 1)];

    __builtin_amdgcn_sched_barrier(0);  // pin: all prefetch issued before compute

    compute_tile(E0, E1, H0, H1, dd, g, m, Bf, out);

    E0 = E0n; E1 = E1n; H0 = H0n; H1 = H1n; dd = ddn; s1 = s2;
    tile = tile1; tile1 = tile2;
  }

  compute_tile(E0, E1, H0, H1, dd, g, m, Bf, out);
}

extern "C" void kernel_launch(void* const* d_in, const int* in_sizes, int n_in,
                              void* d_out, int out_size, void* d_ws, size_t ws_size,
                              hipStream_t stream) {
  const float* feat  = (const float*)d_in[0];
  const float* efeat = (const float*)d_in[1];
  const float* We    = (const float*)d_in[2];
  const float* be    = (const float*)d_in[3];
  const float* bias  = (const float*)d_in[4];
  const int*   src   = (const int*)d_in[5];
  const int*   dst   = (const int*)d_in[6];
  float* out = (float*)d_out;

  int E = in_sizes[5];
  int n_elems = out_size;  // 50000*16

  int groups = (n_elems + 3) / 4;
  int initB = (groups + 255) / 256;
  int prepB = (9 * 4 * 16 * 8 + 255) / 256;
  setup_kernel<<<initB + prepB, 256, 0, stream>>>(feat, bias, We, be, out,
                                                  (unsigned short*)d_ws, n_elems, initB);

  int ntiles = (E + 15) / 16;
  int blocks = min(NBLK, (ntiles + 3) / 4);
  edge_mfma_kernel<<<blocks, 256, 0, stream>>>(feat, efeat, src, dst,
                                               (const unsigned short*)d_ws, out, E);
}